// Round 12
// baseline (1446.540 us; speedup 1.0000x reference)
//
#include <hip/hip_runtime.h>
#include <math.h>

// Problem constants
#define T_DIM 16
#define B_DIM 128
#define N_DIM 2048
#define TB    (T_DIM * B_DIM)   // 2048 rows of the GEMM

// Workspace layout (bytes). Total ~36.75 MB.
#define WS_H      0
#define WS_TSUM   33554432
#define WS_PSUM   35651584      // [32][2048] f64 per-rowband col sums
#define WS_PSUM2  36175872      // [32][2048] f64 per-rowband col sq-sums
#define WS_SSUM   36700160
#define WS_SCALE  36716544
#define WS_SHIFT  36732928
#define WS_FLAG   36749312

typedef __attribute__((ext_vector_type(2))) double d2;
typedef __attribute__((ext_vector_type(4))) double d4;

// ---- MFMA f64 wiring probe -------------------------------------------------
__device__ __forceinline__ double probeA(int m, int k) {
    return (double)((m * 7 + k * 13) % 23 - 11);
}
__device__ __forceinline__ double probeB(int k, int n) {
    return (double)((k * 5 + n * 3) % 19 - 9);
}

// Hypothesis encoding fh = ab*4 + dF;  ab = aF + 2*bF.
//  A-form 0: m=l&15,k=l>>4   1: m=l>>2,k=l&3
//  B-form 0: n=l&15,k=l>>4   1: n=l>>2,k=l&3
//  D-form 0: i=4*(l>>4)+r,j=l&15   1: i=(l>>4)+4r,j=l&15
//         2: j=4*(l>>4)+r,i=l&15   3: j=(l>>4)+4r,i=l&15
__global__ void mfma_probe_kernel(unsigned int* flag) {
    int l = threadIdx.x;                 // one wave
    __shared__ double Cref[16][16];
    int i0 = l >> 2, j0 = (l & 3) << 2;
    for (int jj = 0; jj < 4; ++jj) {
        double s = 0.0;
        for (int k = 0; k < 4; ++k) s += probeA(i0, k) * probeB(k, j0 + jj);
        Cref[i0][j0 + jj] = s;
    }
    __syncthreads();
    unsigned int win = 0xFFFFFFFFu;
    for (int ab = 0; ab < 4; ++ab) {
        int aF = ab & 1, bF = (ab >> 1) & 1;
        int mA = aF ? (l >> 2) : (l & 15);
        int kA = aF ? (l & 3)  : (l >> 4);
        int nB = bF ? (l >> 2) : (l & 15);
        int kB = bF ? (l & 3)  : (l >> 4);
        d4 d = (d4)0.0;
        d = __builtin_amdgcn_mfma_f64_16x16x4f64(probeA(mA, kA), probeB(kB, nB), d, 0, 0, 0);
        for (int dF = 0; dF < 4; ++dF) {
            double err = 0.0;
            for (int r = 0; r < 4; ++r) {
                int ii, jj;
                if (dF == 0)      { ii = 4 * (l >> 4) + r; jj = l & 15; }
                else if (dF == 1) { ii = (l >> 4) + 4 * r; jj = l & 15; }
                else if (dF == 2) { jj = 4 * (l >> 4) + r; ii = l & 15; }
                else              { jj = (l >> 4) + 4 * r; ii = l & 15; }
                err = fmax(err, fabs(d[r] - Cref[ii][jj]));
            }
            for (int off = 1; off < 64; off <<= 1)
                err = fmax(err, __shfl_xor(err, off, 64));
            if (err < 1e-9 && win == 0xFFFFFFFFu)
                win = (unsigned)(ab * 4 + dF);
        }
    }
    if (l == 0) flag[0] = win;
}

// ---- spatial sum over last dim: one block per (t,b) row -------------------
__global__ __launch_bounds__(256)
void spatial_sum_kernel(const float* __restrict__ x, double* __restrict__ ssum) {
    int row = blockIdx.x;
    int tid = threadIdx.x;
    const float* xr = x + (size_t)row * N_DIM;
    double s = 0.0;
    for (int i = tid; i < N_DIM; i += 256) s += (double)xr[i];
    for (int off = 32; off > 0; off >>= 1) s += __shfl_down(s, off, 64);
    __shared__ double wsum[4];
    int lane = tid & 63, wv = tid >> 6;
    if (lane == 0) wsum[wv] = s;
    __syncthreads();
    if (tid == 0) ssum[row] = (wsum[0] + wsum[1]) + (wsum[2] + wsum[3]);
}

// ---- temporal sum over t: one thread per (b,n) ----------------------------
__global__ __launch_bounds__(256)
void temporal_sum_kernel(const float* __restrict__ x, double* __restrict__ tsum) {
    int idx = blockIdx.x * 256 + threadIdx.x;
    double s = 0.0;
    for (int t = 0; t < T_DIM; ++t)
        s += (double)x[(size_t)t * (B_DIM * N_DIM) + idx];
    tsum[idx] = s;
}

// ---- GEMM h[row,m] = sum_n x[row,n] * W[m,n] ------------------------------
// v11: 64x64 tile, FOUR waves/block, 4-way in-block split-K (wave w owns
// k-tiles w*16 + 64i), barrier-free per-wave PRIVATE single-buffer f32
// staging (R10's proven inner loop; double-buffer twice shown neutral).
// Occupancy fix: R11 was grid-limited at 2 waves/SIMD (21.5%); 256-thread
// blocks at 40KB LDS -> 4 blocks/CU * 4 waves = 4 waves/SIMD, pinned by
// __launch_bounds__(256,4) (VGPR<=128; MFMA path used 116).
// Epilogue: sequential deterministic combine acc += w1, w2, w3, then
// C-store + fused layout-agnostic BN partials (64x64 LDS scatter).
#define BK 16
#define STRD 80   // mfma path f32 stride per k-row (2-way aliasing = free)

#define MFMA_LOAD(koff)                                             \
    _Pragma("unroll")                                               \
    for (int j = 0; j < 4; ++j) {                                   \
        sa[j] = *(const float4*)(Ag + (koff) + 4 * j);              \
        sb[j] = *(const float4*)(Bg + (koff) + 4 * j);              \
    }

#define MFMA_STAGE(Ab, Bb)                                          \
    _Pragma("unroll")                                               \
    for (int j = 0; j < 4; ++j) {                                   \
        (Ab)[(4 * j + 0) * STRD + lane] = sa[j].x;                  \
        (Ab)[(4 * j + 1) * STRD + lane] = sa[j].y;                  \
        (Ab)[(4 * j + 2) * STRD + lane] = sa[j].z;                  \
        (Ab)[(4 * j + 3) * STRD + lane] = sa[j].w;                  \
        (Bb)[(4 * j + 0) * STRD + lane] = sb[j].x;                  \
        (Bb)[(4 * j + 1) * STRD + lane] = sb[j].y;                  \
        (Bb)[(4 * j + 2) * STRD + lane] = sb[j].z;                  \
        (Bb)[(4 * j + 3) * STRD + lane] = sb[j].w;                  \
    }

#define MFMA_COMPUTE(Ab, Bb)                                        \
    _Pragma("unroll")                                               \
    for (int jq = 0; jq < 4; ++jq) {                                \
        double av[4], bv[4];                                        \
        _Pragma("unroll")                                           \
        for (int f = 0; f < 4; ++f)                                 \
            av[f] = (double)(Ab)[(4 * jq + kA) * STRD + 16 * f + mA]; \
        _Pragma("unroll")                                           \
        for (int g = 0; g < 4; ++g)                                 \
            bv[g] = (double)(Bb)[(4 * jq + kB) * STRD + 16 * g + nB]; \
        _Pragma("unroll")                                           \
        for (int f = 0; f < 4; ++f)                                 \
            _Pragma("unroll")                                       \
            for (int g = 0; g < 4; ++g)                             \
                acc[f][g] = __builtin_amdgcn_mfma_f64_16x16x4f64(   \
                    av[f], bv[g], acc[f][g], 0, 0, 0);              \
    }

#define CB_DUMP                                                     \
    _Pragma("unroll")                                               \
    for (int f = 0; f < 4; ++f)                                     \
        _Pragma("unroll")                                           \
        for (int g = 0; g < 4; ++g)                                 \
            _Pragma("unroll")                                       \
            for (int r = 0; r < 4; ++r)                             \
                cbuf[((f * 4 + g) * 4 + r) * 64 + lane] = acc[f][g][r];

#define CB_ADD                                                      \
    _Pragma("unroll")                                               \
    for (int f = 0; f < 4; ++f)                                     \
        _Pragma("unroll")                                           \
        for (int g = 0; g < 4; ++g)                                 \
            _Pragma("unroll")                                       \
            for (int r = 0; r < 4; ++r)                             \
                acc[f][g][r] += cbuf[((f * 4 + g) * 4 + r) * 64 + lane];

__global__ __launch_bounds__(256, 4)
void gemm_hybrid(const float* __restrict__ A, const float* __restrict__ Bw,
                 double* __restrict__ C, double* __restrict__ psum,
                 double* __restrict__ psum2, const unsigned int* __restrict__ flag) {
    __shared__ __align__(16) char smem[40960];   // 4 waves x 10240B staging; cbuf 32KB reuse
    const int t    = threadIdx.x;
    const int lane = t & 63;
    const int w    = t >> 6;                     // wave id 0..3
    const int row0 = blockIdx.y * 64;
    const int col0 = blockIdx.x * 64;
    const int band = blockIdx.y;
    const unsigned int fh = flag[0];

    const float* Ag = A  + (size_t)(row0 + lane) * N_DIM;
    const float* Bg = Bw + (size_t)(col0 + lane) * N_DIM;
    const int kw = w * BK;                       // this wave's first k-tile
    double* cbuf = (double*)smem;                // 4096 doubles = 32KB

    if (fh <= 15u) {
        // ================= MFMA path =================
        const int dF = fh & 3, ab = fh >> 2;
        const int aF = ab & 1, bF = (ab >> 1) & 1;
        const int mA = aF ? (lane >> 2) : (lane & 15);
        const int kA = aF ? (lane & 3)  : (lane >> 4);
        const int nB = bF ? (lane >> 2) : (lane & 15);
        const int kB = bF ? (lane & 3)  : (lane >> 4);
        int iD[4], jD[4];
#pragma unroll
        for (int r = 0; r < 4; ++r) {
            if (dF == 0)      { iD[r] = 4 * (lane >> 4) + r; jD[r] = lane & 15; }
            else if (dF == 1) { iD[r] = (lane >> 4) + 4 * r; jD[r] = lane & 15; }
            else if (dF == 2) { jD[r] = 4 * (lane >> 4) + r; iD[r] = lane & 15; }
            else              { jD[r] = (lane >> 4) + 4 * r; iD[r] = lane & 15; }
        }

        float* Asw = (float*)(smem + (size_t)w * 10240);  // 16 x 80 f32
        float* Bsw = Asw + 1280;

        d4 acc[4][4];
#pragma unroll
        for (int f = 0; f < 4; ++f)
#pragma unroll
            for (int g = 0; g < 4; ++g) acc[f][g] = (d4)0.0;

        float4 sa[4], sb[4];
        MFMA_LOAD(kw)                            // tile 0
        for (int k0 = kw; k0 < N_DIM; k0 += 64) {
            MFMA_STAGE(Asw, Bsw)
            if (k0 + 64 < N_DIM) { MFMA_LOAD(k0 + 64) }
            MFMA_COMPUTE(Asw, Bsw)
        }

        // sequential deterministic 4-way combine: acc(w0) += w1, w2, w3
        __syncthreads();
        if (w == 1) { CB_DUMP }
        __syncthreads();
        if (w == 0) { CB_ADD }
        __syncthreads();
        if (w == 2) { CB_DUMP }
        __syncthreads();
        if (w == 0) { CB_ADD }
        __syncthreads();
        if (w == 3) { CB_DUMP }
        __syncthreads();
        if (w == 0) {
            CB_ADD
            // store C
#pragma unroll
            for (int f = 0; f < 4; ++f)
#pragma unroll
                for (int r = 0; r < 4; ++r) {
                    int row = row0 + 16 * f + iD[r];
                    double* Crow = C + (size_t)row * N_DIM + col0 + jD[r];
#pragma unroll
                    for (int g = 0; g < 4; ++g)
                        Crow[16 * g] = acc[f][g][r];
                }
            // layout-agnostic BN partials: scatter acc -> cbuf[row][col],
            // then column-sum (same-wave DS ordering -> no barrier needed)
#pragma unroll
            for (int f = 0; f < 4; ++f)
#pragma unroll
                for (int r = 0; r < 4; ++r)
#pragma unroll
                    for (int g = 0; g < 4; ++g)
                        cbuf[(16 * f + iD[r]) * 64 + 16 * g + jD[r]] = acc[f][g][r];
            double s = 0.0, q = 0.0;
#pragma unroll
            for (int r = 0; r < 64; ++r) {
                double v = cbuf[r * 64 + lane];
                s += v;
                q = fma(v, v, q);
            }
            psum [band * N_DIM + col0 + lane] = s;
            psum2[band * N_DIM + col0 + lane] = q;
        }
    } else {
        // ====== vector fallback (R1-style 256-thread 64x64, 4x4 acc) ======
        const int tx = t & 15;                   // col group
        const int ty = t >> 4;                   // row group
        double* As = (double*)smem;              // [16][65] doubles
        double* Bs = As + 16 * 65;               // [16][65] doubles (33.8KB total? no:)
        // 2*16*65*8 = 16640B -> fits in 40960.
        int lr = t >> 2;                         // tile row staged
        int lk = (t & 3) * 4;                    // k offset
        const float* Aptr = A  + (size_t)(row0 + lr) * N_DIM + lk;
        const float* Bptr = Bw + (size_t)(col0 + lr) * N_DIM + lk;

        double acc[4][4];
#pragma unroll
        for (int i = 0; i < 4; ++i)
#pragma unroll
            for (int j = 0; j < 4; ++j) acc[i][j] = 0.0;

        for (int k0 = 0; k0 < N_DIM; k0 += BK) {
            float4 a4 = *(const float4*)(Aptr + k0);
            float4 b4 = *(const float4*)(Bptr + k0);
            __syncthreads();
            As[(lk + 0) * 65 + lr] = (double)a4.x;
            As[(lk + 1) * 65 + lr] = (double)a4.y;
            As[(lk + 2) * 65 + lr] = (double)a4.z;
            As[(lk + 3) * 65 + lr] = (double)a4.w;
            Bs[(lk + 0) * 65 + lr] = (double)b4.x;
            Bs[(lk + 1) * 65 + lr] = (double)b4.y;
            Bs[(lk + 2) * 65 + lr] = (double)b4.z;
            Bs[(lk + 3) * 65 + lr] = (double)b4.w;
            __syncthreads();
#pragma unroll
            for (int k = 0; k < BK; ++k) {
                double av[4], bv[4];
#pragma unroll
                for (int i = 0; i < 4; ++i) av[i] = As[k * 65 + ty + 16 * i];
#pragma unroll
                for (int j = 0; j < 4; ++j) bv[j] = Bs[k * 65 + tx + 16 * j];
#pragma unroll
                for (int i = 0; i < 4; ++i)
#pragma unroll
                    for (int j = 0; j < 4; ++j)
                        acc[i][j] = fma(av[i], bv[j], acc[i][j]);
            }
        }
        __syncthreads();
#pragma unroll
        for (int i = 0; i < 4; ++i) {
            int r = row0 + ty + 16 * i;
#pragma unroll
            for (int j = 0; j < 4; ++j)
                C[(size_t)r * N_DIM + col0 + tx + 16 * j] = acc[i][j];
        }
        // BN partials via cbuf scatter (64x64 doubles = 32KB)
#pragma unroll
        for (int i = 0; i < 4; ++i)
#pragma unroll
            for (int j = 0; j < 4; ++j)
                cbuf[(ty + 16 * i) * 64 + tx + 16 * j] = acc[i][j];
        __syncthreads();
        if (t < 64) {
            double s = 0.0, q = 0.0;
            for (int r = 0; r < 64; ++r) {
                double v = cbuf[r * 64 + t];
                s += v;
                q = fma(v, v, q);
            }
            psum [band * N_DIM + col0 + t] = s;
            psum2[band * N_DIM + col0 + t] = q;
        }
    }
}

// ---- BN final: reduce 32 rowband partials, build scale/shift --------------
__global__ __launch_bounds__(256)
void col_stats_final(const double* __restrict__ psum, const double* __restrict__ psum2,
                     const float* __restrict__ gamma, const float* __restrict__ beta,
                     double* __restrict__ scale, double* __restrict__ shift) {
    int m = blockIdx.x * 256 + threadIdx.x;
    double s = 0.0, s2 = 0.0;
    for (int c = 0; c < 32; ++c) { s += psum[c * N_DIM + m]; s2 += psum2[c * N_DIM + m]; }
    double mean = s * (1.0 / 2048.0);
    double var = s2 * (1.0 / 2048.0) - mean * mean;
    double istd = 1.0 / sqrt(var + 1e-5);
    double sc = istd * (double)gamma[m];
    scale[m] = sc;
    shift[m] = (double)beta[m] - mean * sc;
}

// ---- fused BN-apply + triple LIF + output ---------------------------------
__global__ __launch_bounds__(256)
void fused_lif_kernel(const float* __restrict__ x, const double* __restrict__ h,
                      const double* __restrict__ scale, const double* __restrict__ shift,
                      const double* __restrict__ ssum, const double* __restrict__ tsum,
                      float* __restrict__ out) {
    int idx = blockIdx.x * 256 + threadIdx.x;
    int n = idx & (N_DIM - 1);
    int b = idx >> 11;
    double sc = scale[n], sh = shift[n];
    double ts = tsum[idx];
    double v1 = 0.0, v2 = 0.0, v3 = 0.0;
    for (int t = 0; t < T_DIM; ++t) {
        size_t off = (size_t)(t * B_DIM + b) * N_DIM + n;
        double hv = fma(h[off], sc, sh);
        v1 = v1 * 0.5 + hv;
        bool s1 = (v1 >= 1.0); if (s1) v1 = 0.0;
        double in2 = s1 ? ssum[t * B_DIM + b] : 0.0;
        v2 = v2 * 0.5 + in2;
        bool s2 = (v2 >= 1.0); if (s2) v2 = 0.0;
        double in3 = s1 ? ts : 0.0;
        v3 = v3 * 0.5 + in3;
        bool s3 = (v3 >= 1.0); if (s3) v3 = 0.0;
        out[off] = x[off] + ((s2 && s3) ? 1.0f : 0.0f);
    }
}

extern "C" void kernel_launch(void* const* d_in, const int* in_sizes, int n_in,
                              void* d_out, int out_size, void* d_ws, size_t ws_size,
                              hipStream_t stream) {
    const float* x     = (const float*)d_in[0];   // [16,128,2048]
    const float* W     = (const float*)d_in[1];   // [2048,2048]
    const float* gamma = (const float*)d_in[2];   // [2048]
    const float* beta  = (const float*)d_in[3];   // [2048]
    float* out = (float*)d_out;

    char* ws = (char*)d_ws;
    double* h     = (double*)(ws + WS_H);
    double* tsum  = (double*)(ws + WS_TSUM);
    double* psum  = (double*)(ws + WS_PSUM);
    double* psum2 = (double*)(ws + WS_PSUM2);
    double* ssum  = (double*)(ws + WS_SSUM);
    double* scale = (double*)(ws + WS_SCALE);
    double* shift = (double*)(ws + WS_SHIFT);
    unsigned int* flag = (unsigned int*)(ws + WS_FLAG);

    mfma_probe_kernel<<<1, 64, 0, stream>>>(flag);
    spatial_sum_kernel<<<TB, 256, 0, stream>>>(x, ssum);
    temporal_sum_kernel<<<(B_DIM * N_DIM) / 256, 256, 0, stream>>>(x, tsum);
    gemm_hybrid<<<dim3(N_DIM / 64, TB / 64), 256, 0, stream>>>(x, W, h, psum, psum2, flag);
    col_stats_final<<<8, 256, 0, stream>>>(psum, psum2, gamma, beta, scale, shift);
    fused_lif_kernel<<<(B_DIM * N_DIM) / 256, 256, 0, stream>>>(x, h, scale, shift, ssum, tsum, out);
}

// Round 13
// 381.029 us; speedup vs baseline: 3.7964x; 3.7964x over previous
//
#include <hip/hip_runtime.h>
#include <math.h>

// Problem constants
#define T_DIM 16
#define B_DIM 128
#define N_DIM 2048
#define TB    (T_DIM * B_DIM)   // 2048 rows of the GEMM

// Workspace layout (bytes). Total ~36.75 MB (same as R11, proven to fit).
#define WS_H      0
#define WS_TSUM   33554432
#define WS_PSUM   35651584      // [32][2048] f64 per-rowband col sums
#define WS_PSUM2  36175872      // [32][2048] f64 per-rowband col sq-sums
#define WS_SSUM   36700160
#define WS_SCALE  36716544
#define WS_SHIFT  36732928
#define WS_FLAG   36749312

typedef __attribute__((ext_vector_type(4))) double d4;

// ---- MFMA f64 wiring probe -------------------------------------------------
__device__ __forceinline__ double probeA(int m, int k) {
    return (double)((m * 7 + k * 13) % 23 - 11);
}
__device__ __forceinline__ double probeB(int k, int n) {
    return (double)((k * 5 + n * 3) % 19 - 9);
}

// Hypothesis encoding fh = ab*4 + dF;  ab = aF + 2*bF.
//  A-form 0: m=l&15,k=l>>4   1: m=l>>2,k=l&3
//  B-form 0: n=l&15,k=l>>4   1: n=l>>2,k=l&3
//  D-form 0: i=4*(l>>4)+r,j=l&15   1: i=(l>>4)+4r,j=l&15
//         2: j=4*(l>>4)+r,i=l&15   3: j=(l>>4)+4r,i=l&15
__global__ void mfma_probe_kernel(unsigned int* flag) {
    int l = threadIdx.x;                 // one wave
    __shared__ double Cref[16][16];
    int i0 = l >> 2, j0 = (l & 3) << 2;
    for (int jj = 0; jj < 4; ++jj) {
        double s = 0.0;
        for (int k = 0; k < 4; ++k) s += probeA(i0, k) * probeB(k, j0 + jj);
        Cref[i0][j0 + jj] = s;
    }
    __syncthreads();
    unsigned int win = 0xFFFFFFFFu;
    for (int ab = 0; ab < 4; ++ab) {
        int aF = ab & 1, bF = (ab >> 1) & 1;
        int mA = aF ? (l >> 2) : (l & 15);
        int kA = aF ? (l & 3)  : (l >> 4);
        int nB = bF ? (l >> 2) : (l & 15);
        int kB = bF ? (l & 3)  : (l >> 4);
        d4 d = (d4)0.0;
        d = __builtin_amdgcn_mfma_f64_16x16x4f64(probeA(mA, kA), probeB(kB, nB), d, 0, 0, 0);
        for (int dF = 0; dF < 4; ++dF) {
            double err = 0.0;
            for (int r = 0; r < 4; ++r) {
                int ii, jj;
                if (dF == 0)      { ii = 4 * (l >> 4) + r; jj = l & 15; }
                else if (dF == 1) { ii = (l >> 4) + 4 * r; jj = l & 15; }
                else if (dF == 2) { jj = 4 * (l >> 4) + r; ii = l & 15; }
                else              { jj = (l >> 4) + 4 * r; ii = l & 15; }
                err = fmax(err, fabs(d[r] - Cref[ii][jj]));
            }
            for (int off = 1; off < 64; off <<= 1)
                err = fmax(err, __shfl_xor(err, off, 64));
            if (err < 1e-9 && win == 0xFFFFFFFFu)
                win = (unsigned)(ab * 4 + dF);
        }
    }
    if (l == 0) flag[0] = win;
}

// ---- spatial sum over last dim: one block per (t,b) row -------------------
__global__ __launch_bounds__(256)
void spatial_sum_kernel(const float* __restrict__ x, double* __restrict__ ssum) {
    int row = blockIdx.x;
    int tid = threadIdx.x;
    const float* xr = x + (size_t)row * N_DIM;
    double s = 0.0;
    for (int i = tid; i < N_DIM; i += 256) s += (double)xr[i];
    for (int off = 32; off > 0; off >>= 1) s += __shfl_down(s, off, 64);
    __shared__ double wsum[4];
    int lane = tid & 63, wv = tid >> 6;
    if (lane == 0) wsum[wv] = s;
    __syncthreads();
    if (tid == 0) ssum[row] = (wsum[0] + wsum[1]) + (wsum[2] + wsum[3]);
}

// ---- temporal sum over t: one thread per (b,n) ----------------------------
__global__ __launch_bounds__(256)
void temporal_sum_kernel(const float* __restrict__ x, double* __restrict__ tsum) {
    int idx = blockIdx.x * 256 + threadIdx.x;
    double s = 0.0;
    for (int t = 0; t < T_DIM; ++t)
        s += (double)x[(size_t)t * (B_DIM * N_DIM) + idx];
    tsum[idx] = s;
}

// ---- GEMM h[row,m] = sum_n x[row,n] * W[m,n] ------------------------------
// v12: 64x64 block tile, FOUR waves/block, each wave owns a 32x32 QUADRANT
// (2x2 f64-MFMA tiles = only 32 acc regs/lane; R12's spill was the 16-tile
// 128-reg accumulator under a 128-reg launch_bounds cap). Full-K per wave:
// k ascending -> h bit-identical to R1's order (absmax 0.0 lineage).
// Cooperative SHARED staging (10KB, [k][row] f32 stride 80), m97-style
// 2-barrier loop with register prefetch. ~4 blocks/CU co-resident overlap
// the barrier drains (m114). Probe-adaptive fragment wiring as R10-R11.
// Epilogue: quadrant C-store (no cross-wave combine), then layout-agnostic
// BN partials: per-wave 32x32 LDS scatter (2 rounds of 2 waves in 16KB) +
// cross-wave pcol combine -> psum/psum2[band=blockIdx.y].
#define BK 16
#define STRD 80   // f32 stride per k-row

__global__ __launch_bounds__(256, 3)
void gemm_hybrid(const float* __restrict__ A, const float* __restrict__ Bw,
                 double* __restrict__ C, double* __restrict__ psum,
                 double* __restrict__ psum2, const unsigned int* __restrict__ flag) {
    __shared__ __align__(16) char smem[17408];   // staging 10240 / scatter 16384 + pcol 1024
    const int t    = threadIdx.x;
    const int lane = t & 63;
    const int w    = t >> 6;                     // wave id 0..3
    const int row0 = blockIdx.y * 64;
    const int col0 = blockIdx.x * 64;
    const int band = blockIdx.y;
    const unsigned int fh = flag[0];

    float* As = (float*)smem;                    // 16 x 80 f32 = 5120B
    float* Bs = As + 1280;                       // 5120B
    double* pcol_s = (double*)(smem + 16384);    // 64 doubles
    double* pcol_q = pcol_s + 64;                // 64 doubles

    // cooperative staging assignment: thread t loads one float4 of A and B
    const int r_st  = t >> 2;                    // tile row 0..63
    const int kq_st = t & 3;                     // k-offset group
    const float* Ag = A  + (size_t)(row0 + r_st) * N_DIM + kq_st * 4;
    const float* Bg = Bw + (size_t)(col0 + r_st) * N_DIM + kq_st * 4;

    if (fh <= 15u) {
        // ================= MFMA path =================
        const int dF = fh & 3, ab = fh >> 2;
        const int aF = ab & 1, bF = (ab >> 1) & 1;
        const int mA = aF ? (lane >> 2) : (lane & 15);
        const int kA = aF ? (lane & 3)  : (lane >> 4);
        const int nB = bF ? (lane >> 2) : (lane & 15);
        const int kB = bF ? (lane & 3)  : (lane >> 4);
        int iD[4], jD[4];
#pragma unroll
        for (int r = 0; r < 4; ++r) {
            if (dF == 0)      { iD[r] = 4 * (lane >> 4) + r; jD[r] = lane & 15; }
            else if (dF == 1) { iD[r] = (lane >> 4) + 4 * r; jD[r] = lane & 15; }
            else if (dF == 2) { jD[r] = 4 * (lane >> 4) + r; iD[r] = lane & 15; }
            else              { jD[r] = (lane >> 4) + 4 * r; iD[r] = lane & 15; }
        }
        const int m0 = (w & 1) * 32;             // quadrant offsets
        const int n0 = (w >> 1) * 32;

        d4 acc[2][2];
#pragma unroll
        for (int f = 0; f < 2; ++f)
#pragma unroll
            for (int g = 0; g < 2; ++g) acc[f][g] = (d4)0.0;

        float4 a4 = *(const float4*)(Ag);        // tile 0 prefetch
        float4 b4 = *(const float4*)(Bg);

        for (int k0 = 0; k0 < N_DIM; k0 += BK) {
            __syncthreads();                     // prev compute done reading
            As[(4 * kq_st + 0) * STRD + r_st] = a4.x;
            As[(4 * kq_st + 1) * STRD + r_st] = a4.y;
            As[(4 * kq_st + 2) * STRD + r_st] = a4.z;
            As[(4 * kq_st + 3) * STRD + r_st] = a4.w;
            Bs[(4 * kq_st + 0) * STRD + r_st] = b4.x;
            Bs[(4 * kq_st + 1) * STRD + r_st] = b4.y;
            Bs[(4 * kq_st + 2) * STRD + r_st] = b4.z;
            Bs[(4 * kq_st + 3) * STRD + r_st] = b4.w;
            if (k0 + BK < N_DIM) {               // register prefetch next tile
                a4 = *(const float4*)(Ag + k0 + BK);
                b4 = *(const float4*)(Bg + k0 + BK);
            }
            __syncthreads();                     // staging visible
#pragma unroll
            for (int jq = 0; jq < 4; ++jq) {     // 4 k-quads, ascending
                double av[2], bv[2];
#pragma unroll
                for (int f = 0; f < 2; ++f)
                    av[f] = (double)As[(4 * jq + kA) * STRD + m0 + 16 * f + mA];
#pragma unroll
                for (int g = 0; g < 2; ++g)
                    bv[g] = (double)Bs[(4 * jq + kB) * STRD + n0 + 16 * g + nB];
#pragma unroll
                for (int f = 0; f < 2; ++f)
#pragma unroll
                    for (int g = 0; g < 2; ++g)
                        acc[f][g] = __builtin_amdgcn_mfma_f64_16x16x4f64(
                            av[f], bv[g], acc[f][g], 0, 0, 0);
            }
        }

        // ---- C store: each wave stores its own quadrant (no combine) ----
#pragma unroll
        for (int f = 0; f < 2; ++f)
#pragma unroll
            for (int r = 0; r < 4; ++r) {
                int row = row0 + m0 + 16 * f + iD[r];
                double* Crow = C + (size_t)row * N_DIM + col0 + n0 + jD[r];
#pragma unroll
                for (int g = 0; g < 2; ++g)
                    Crow[16 * g] = acc[f][g][r];
            }

        // ---- BN partials: layout-agnostic scatter, 2 rounds of 2 waves ----
        double s = 0.0, q = 0.0;
        __syncthreads();                         // main-loop staging reads done
        if (w < 2) {
            double* sc = (double*)(smem + (size_t)w * 8192);   // 32x32 doubles
#pragma unroll
            for (int f = 0; f < 2; ++f)
#pragma unroll
                for (int r = 0; r < 4; ++r)
#pragma unroll
                    for (int g = 0; g < 2; ++g)
                        sc[(16 * f + iD[r]) * 32 + 16 * g + jD[r]] = acc[f][g][r];
            if (lane < 32) {                     // same-wave DS order: no barrier
                for (int r = 0; r < 32; ++r) {
                    double v = sc[r * 32 + lane];
                    s += v;
                    q = fma(v, v, q);
                }
            }
        }
        __syncthreads();
        if (w >= 2) {
            double* sc = (double*)(smem + (size_t)(w - 2) * 8192);
#pragma unroll
            for (int f = 0; f < 2; ++f)
#pragma unroll
                for (int r = 0; r < 4; ++r)
#pragma unroll
                    for (int g = 0; g < 2; ++g)
                        sc[(16 * f + iD[r]) * 32 + 16 * g + jD[r]] = acc[f][g][r];
            if (lane < 32) {
                for (int r = 0; r < 32; ++r) {
                    double v = sc[r * 32 + lane];
                    s += v;
                    q = fma(v, v, q);
                }
            }
        }
        __syncthreads();
        if ((w & 1) == 1 && lane < 32) {         // m0=32 waves publish
            pcol_s[n0 + lane] = s;
            pcol_q[n0 + lane] = q;
        }
        __syncthreads();
        if ((w & 1) == 0 && lane < 32) {         // m0=0 waves combine + store
            s += pcol_s[n0 + lane];
            q += pcol_q[n0 + lane];
            psum [band * N_DIM + col0 + n0 + lane] = s;
            psum2[band * N_DIM + col0 + n0 + lane] = q;
        }
    } else {
        // ====== vector fallback (R1-style 256-thread 64x64, 4x4 acc) ======
        const int tx = t & 15;                   // col group
        const int ty = t >> 4;                   // row group
        double acc[4][4];
#pragma unroll
        for (int i = 0; i < 4; ++i)
#pragma unroll
            for (int j = 0; j < 4; ++j) acc[i][j] = 0.0;

        float4 a4 = *(const float4*)(Ag);
        float4 b4 = *(const float4*)(Bg);
        for (int k0 = 0; k0 < N_DIM; k0 += BK) {
            __syncthreads();
            As[(4 * kq_st + 0) * STRD + r_st] = a4.x;
            As[(4 * kq_st + 1) * STRD + r_st] = a4.y;
            As[(4 * kq_st + 2) * STRD + r_st] = a4.z;
            As[(4 * kq_st + 3) * STRD + r_st] = a4.w;
            Bs[(4 * kq_st + 0) * STRD + r_st] = b4.x;
            Bs[(4 * kq_st + 1) * STRD + r_st] = b4.y;
            Bs[(4 * kq_st + 2) * STRD + r_st] = b4.z;
            Bs[(4 * kq_st + 3) * STRD + r_st] = b4.w;
            if (k0 + BK < N_DIM) {
                a4 = *(const float4*)(Ag + k0 + BK);
                b4 = *(const float4*)(Bg + k0 + BK);
            }
            __syncthreads();
#pragma unroll
            for (int k = 0; k < BK; ++k) {
                double av[4], bv[4];
#pragma unroll
                for (int i = 0; i < 4; ++i) av[i] = (double)As[k * STRD + ty + 16 * i];
#pragma unroll
                for (int j = 0; j < 4; ++j) bv[j] = (double)Bs[k * STRD + tx + 16 * j];
#pragma unroll
                for (int i = 0; i < 4; ++i)
#pragma unroll
                    for (int j = 0; j < 4; ++j)
                        acc[i][j] = fma(av[i], bv[j], acc[i][j]);
            }
        }
#pragma unroll
        for (int i = 0; i < 4; ++i) {
            int r = row0 + ty + 16 * i;
#pragma unroll
            for (int j = 0; j < 4; ++j)
                C[(size_t)r * N_DIM + col0 + tx + 16 * j] = acc[i][j];
        }
        // BN partials: per-thread 4-row partial -> pband[16][64] -> reduce
        __syncthreads();
        double* pb_s = (double*)smem;            // 16*64 doubles = 8KB
        double* pb_q = pb_s + 1024;              // 8KB
#pragma unroll
        for (int j = 0; j < 4; ++j) {
            double s = 0.0, q = 0.0;
#pragma unroll
            for (int i = 0; i < 4; ++i) {
                double v = acc[i][j];
                s += v;
                q = fma(v, v, q);
            }
            pb_s[ty * 64 + tx + 16 * j] = s;
            pb_q[ty * 64 + tx + 16 * j] = q;
        }
        __syncthreads();
        if (t < 64) {
            double s = 0.0, q = 0.0;
            for (int g = 0; g < 16; ++g) {       // ascending row-group order
                s += pb_s[g * 64 + t];
                q += pb_q[g * 64 + t];
            }
            psum [band * N_DIM + col0 + t] = s;
            psum2[band * N_DIM + col0 + t] = q;
        }
    }
}

// ---- BN final: reduce 32 rowband partials, build scale/shift --------------
__global__ __launch_bounds__(256)
void col_stats_final(const double* __restrict__ psum, const double* __restrict__ psum2,
                     const float* __restrict__ gamma, const float* __restrict__ beta,
                     double* __restrict__ scale, double* __restrict__ shift) {
    int m = blockIdx.x * 256 + threadIdx.x;
    double s = 0.0, s2 = 0.0;
    for (int c = 0; c < 32; ++c) { s += psum[c * N_DIM + m]; s2 += psum2[c * N_DIM + m]; }
    double mean = s * (1.0 / 2048.0);
    double var = s2 * (1.0 / 2048.0) - mean * mean;
    double istd = 1.0 / sqrt(var + 1e-5);
    double sc = istd * (double)gamma[m];
    scale[m] = sc;
    shift[m] = (double)beta[m] - mean * sc;
}

// ---- fused BN-apply + triple LIF + output ---------------------------------
__global__ __launch_bounds__(256)
void fused_lif_kernel(const float* __restrict__ x, const double* __restrict__ h,
                      const double* __restrict__ scale, const double* __restrict__ shift,
                      const double* __restrict__ ssum, const double* __restrict__ tsum,
                      float* __restrict__ out) {
    int idx = blockIdx.x * 256 + threadIdx.x;
    int n = idx & (N_DIM - 1);
    int b = idx >> 11;
    double sc = scale[n], sh = shift[n];
    double ts = tsum[idx];
    double v1 = 0.0, v2 = 0.0, v3 = 0.0;
    for (int t = 0; t < T_DIM; ++t) {
        size_t off = (size_t)(t * B_DIM + b) * N_DIM + n;
        double hv = fma(h[off], sc, sh);
        v1 = v1 * 0.5 + hv;
        bool s1 = (v1 >= 1.0); if (s1) v1 = 0.0;
        double in2 = s1 ? ssum[t * B_DIM + b] : 0.0;
        v2 = v2 * 0.5 + in2;
        bool s2 = (v2 >= 1.0); if (s2) v2 = 0.0;
        double in3 = s1 ? ts : 0.0;
        v3 = v3 * 0.5 + in3;
        bool s3 = (v3 >= 1.0); if (s3) v3 = 0.0;
        out[off] = x[off] + ((s2 && s3) ? 1.0f : 0.0f);
    }
}

extern "C" void kernel_launch(void* const* d_in, const int* in_sizes, int n_in,
                              void* d_out, int out_size, void* d_ws, size_t ws_size,
                              hipStream_t stream) {
    const float* x     = (const float*)d_in[0];   // [16,128,2048]
    const float* W     = (const float*)d_in[1];   // [2048,2048]
    const float* gamma = (const float*)d_in[2];   // [2048]
    const float* beta  = (const float*)d_in[3];   // [2048]
    float* out = (float*)d_out;

    char* ws = (char*)d_ws;
    double* h     = (double*)(ws + WS_H);
    double* tsum  = (double*)(ws + WS_TSUM);
    double* psum  = (double*)(ws + WS_PSUM);
    double* psum2 = (double*)(ws + WS_PSUM2);
    double* ssum  = (double*)(ws + WS_SSUM);
    double* scale = (double*)(ws + WS_SCALE);
    double* shift = (double*)(ws + WS_SHIFT);
    unsigned int* flag = (unsigned int*)(ws + WS_FLAG);

    mfma_probe_kernel<<<1, 64, 0, stream>>>(flag);
    spatial_sum_kernel<<<TB, 256, 0, stream>>>(x, ssum);
    temporal_sum_kernel<<<(B_DIM * N_DIM) / 256, 256, 0, stream>>>(x, tsum);
    gemm_hybrid<<<dim3(N_DIM / 64, TB / 64), 256, 0, stream>>>(x, W, h, psum, psum2, flag);
    col_stats_final<<<8, 256, 0, stream>>>(psum, psum2, gamma, beta, scale, shift);
    fused_lif_kernel<<<(B_DIM * N_DIM) / 256, 256, 0, stream>>>(x, h, scale, shift, ssum, tsum, out);
}